// Round 10
// baseline (38.906 us; speedup 1.0000x reference)
//
#include <hip/hip_runtime.h>
#include <hip/hip_bf16.h>

// Problem constants (from reference setup_inputs)
#define B_   8
#define T_   4096
#define D_   1024
#define DENT 256
#define F_   1280          // D_ + DENT
#define E_   32            // MAX_EVENTS
#define TVOCAB 512
#define THRB 0x40000000u   // __float_as_uint(2.0f)

typedef short  bf16x8 __attribute__((ext_vector_type(8)));
typedef float  f32x16 __attribute__((ext_vector_type(16)));

// RNE f32 pair -> packed bf16x2 (proven numerics, rounds 9)
#define PKBF(x, y) \
    ( ((__float_as_uint(x) + 0x7FFFu + ((__float_as_uint(x) >> 16) & 1u)) >> 16) | \
      ((__float_as_uint(y) + 0x7FFFu + ((__float_as_uint(y) >> 16) & 1u)) & 0xFFFF0000u) )

// ---------------------------------------------------------------------------
// Single fused kernel: 256 blocks x 256 threads.
//   Blocks with yc==0 (8 blocks, batch b = xr): run event selection (radix
//   top-32, exact lax.top_k semantics), publish times/valid via agent-scope
//   atomics, release flags[b].
//   ALL blocks: preload 20 B-fragments (W, select-independent) into regs
//   (overlaps select), spin-acquire flags[xr], direct-load A fragments,
//   20 x mfma_f32_32x32x16_bf16, cross-wave LDS reduce, fused epilogue.
// Co-residency guaranteed by __launch_bounds__(256,2) (>=2 blocks/CU -> all
// 256 blocks resident), so the flag handshake cannot deadlock.
// ---------------------------------------------------------------------------
__global__ __launch_bounds__(256, 2) void k_fused(
    const float* __restrict__ h_seq, const float* __restrict__ z,
    const float* __restrict__ ent, const float* __restrict__ W,
    const float* __restrict__ bias, const float* __restrict__ temb,
    int* __restrict__ ws_times, int* __restrict__ ws_valid,
    int* __restrict__ flags,
    float* __restrict__ out_tape, float* __restrict__ out_valid,
    float* __restrict__ out_times)
{
    __shared__ unsigned s_hist[4 * 257];
    __shared__ unsigned s_tot[256];
    __shared__ int s_cnt, s_nsel, s_bbin, s_prev;
    __shared__ unsigned s_bcg;
    __shared__ int s_selt[E_], s_sorted[E_], s_red[4];
    __shared__ float Red[4][32][36];        // cross-wave k-reduction

    const int tid   = threadIdx.x;
    const int flat  = blockIdx.x;
    const int xcd   = flat & 7;
    const int ib    = flat >> 3;
    const int combo = xcd * 32 + ib;        // bijective 0..255
    const int yc    = combo >> 3;           // col tile 0..31
    const int xr    = combo & 7;            // row tile == batch 0..7
    const bool is_sel = (yc == 0);          // 8 blocks; batch = xr

    // ======================= SELECT PHASE (8 blocks) =======================
    if (is_sel) {
        const int b     = xr;
        const int lane_ = tid & 63;
        const int wid   = tid >> 6;         // wave 0..3

        if (tid == 0) { s_cnt = 0; s_nsel = 0; }
        __syncthreads();

        unsigned key[16];
        int cnt = 0;
        const float* zb = z + (size_t)b * T_ * 8;
        #pragma unroll
        for (int j = 0; j < 16; ++j) {
            const int t = tid + j * 256;
            const float* zp = zb + (size_t)t * 8;
            float4 z0 = *(const float4*)(zp);
            float4 z1 = *(const float4*)(zp + 4);
            float m = fmaxf(fmaxf(fmaxf(fabsf(z0.x), fabsf(z0.y)),
                                  fmaxf(fabsf(z0.z), fabsf(z0.w))),
                            fmaxf(fmaxf(fabsf(z1.x), fabsf(z1.y)),
                                  fmaxf(fabsf(z1.z), fabsf(z1.w))));
            key[j] = __float_as_uint(m);
            if (key[j] > THRB) cnt++;
        }
        #pragma unroll
        for (int off = 32; off > 0; off >>= 1) cnt += __shfl_down(cnt, off);
        if (lane_ == 0) atomicAdd(&s_cnt, cnt);
        __syncthreads();

        const int  n_ev = s_cnt;
        const bool fb   = (n_ev < 4);
        const int  V    = fb ? E_ : (n_ev < E_ ? n_ev : E_);

        if (!fb && n_ev <= E_) {
            #pragma unroll
            for (int j = 0; j < 16; ++j)
                if (key[j] > THRB) { int p = atomicAdd(&s_nsel, 1); s_selt[p] = tid + j * 256; }
            __syncthreads();
        } else {
            unsigned prefix = 0;
            int need = E_;
            for (int p = 0; p < 4; ++p) {
                const int shift = 24 - 8 * p;
                for (int i = tid; i < 4 * 257; i += 256) s_hist[i] = 0;
                __syncthreads();
                unsigned* h = s_hist + wid * 257;
                #pragma unroll
                for (int j = 0; j < 16; ++j) {
                    bool elig = fb || (key[j] > THRB);
                    if (elig && (p == 0 || (key[j] >> (shift + 8)) == prefix))
                        atomicAdd(&h[(key[j] >> shift) & 255u], 1u);
                }
                __syncthreads();
                {   // merge 4 wave-histograms (all 256 threads)
                    unsigned s = s_hist[tid] + s_hist[257 + tid]
                               + s_hist[2 * 257 + tid] + s_hist[3 * 257 + tid];
                    s_tot[tid] = s;
                }
                __syncthreads();
                if (tid < 64) {
                    unsigned b0 = s_tot[4*tid+0], b1 = s_tot[4*tid+1];
                    unsigned b2 = s_tot[4*tid+2], b3 = s_tot[4*tid+3];
                    unsigned lsum = b0 + b1 + b2 + b3;
                    unsigned suf = lsum;                 // inclusive suffix
                    #pragma unroll
                    for (int off = 1; off < 64; off <<= 1) {
                        unsigned o = __shfl_down(suf, off);
                        if (tid + off < 64) suf += o;
                    }
                    unsigned excl = suf - lsum;
                    unsigned cg3 = excl;
                    unsigned cg2 = cg3 + b3;
                    unsigned cg1 = cg2 + b2;
                    unsigned cg0 = cg1 + b1;
                    unsigned un  = (unsigned)need;
                    if (cg3 < un && cg3 + b3 >= un) { s_bbin = 4*tid+3; s_bcg = cg3; }
                    if (cg2 < un && cg2 + b2 >= un) { s_bbin = 4*tid+2; s_bcg = cg2; }
                    if (cg1 < un && cg1 + b1 >= un) { s_bbin = 4*tid+1; s_bcg = cg1; }
                    if (cg0 < un && cg0 + b0 >= un) { s_bbin = 4*tid+0; s_bcg = cg0; }
                }
                __syncthreads();
                need  -= (int)s_bcg;
                prefix = (prefix << 8) | (unsigned)s_bbin;
                __syncthreads();
            }
            const unsigned vstar   = prefix;
            const int      need_eq = need;

            #pragma unroll
            for (int j = 0; j < 16; ++j) {
                bool elig = fb || (key[j] > THRB);
                if (elig && key[j] > vstar) { int p = atomicAdd(&s_nsel, 1); s_selt[p] = tid + j * 256; }
            }
            __syncthreads();
            int prev = -1;
            const int base = s_nsel;
            for (int q = 0; q < need_eq; ++q) {
                int best = 0x7fffffff;
                #pragma unroll
                for (int j = 0; j < 16; ++j) {
                    bool elig = fb || (key[j] > THRB);
                    int  t    = tid + j * 256;
                    if (elig && key[j] == vstar && t > prev && t < best) best = t;
                }
                #pragma unroll
                for (int off = 32; off > 0; off >>= 1) {
                    int o = __shfl_down(best, off);
                    if (o < best) best = o;
                }
                if (lane_ == 0) s_red[wid] = best;
                __syncthreads();
                if (tid == 0) {
                    int m = s_red[0];
                    #pragma unroll
                    for (int w = 1; w < 4; ++w) if (s_red[w] < m) m = s_red[w];
                    s_selt[base + q] = m;
                    s_prev = m;
                }
                __syncthreads();
                prev = s_prev;
            }
        }

        // rank-sort ascending by time
        if (tid < V) {
            int ti = s_selt[tid];
            int rank = 0;
            for (int j = 0; j < V; ++j) rank += (s_selt[j] < ti);
            s_sorted[rank] = ti;
        }
        __syncthreads();
        if (tid < E_) {
            int valid = (tid < V) ? 1 : 0;
            int t     = valid ? s_sorted[tid] : 0;
            __hip_atomic_store(&ws_times[b * E_ + tid], t,
                               __ATOMIC_RELAXED, __HIP_MEMORY_SCOPE_AGENT);
            __hip_atomic_store(&ws_valid[b * E_ + tid], valid,
                               __ATOMIC_RELAXED, __HIP_MEMORY_SCOPE_AGENT);
            out_times[b * E_ + tid] = (float)t;
            out_valid[b * E_ + tid] = (float)valid;
        }
        __syncthreads();   // all publishes complete (vmcnt drained)
        if (tid == 0)
            __hip_atomic_store(&flags[b], 1,
                               __ATOMIC_RELEASE, __HIP_MEMORY_SCOPE_AGENT);
    }

    // ========================= GEMM PHASE (all) ===========================
    const int row0 = xr * 32, col0 = yc * 32;
    const int lane = tid & 63;
    const int wv   = tid >> 6;             // wave -> k-slice [wv*320, +320)
    const int frow = lane & 31;            // A row / B col
    const int kq   = (lane >> 5) * 8;      // k sub-offset within fragment

    // ---- B fragments from W (select-independent; overlaps select) ----
    const size_t wb = (size_t)(col0 + frow) * F_ + kq;
    bf16x8 bfr[20];
    #pragma unroll
    for (int m = 0; m < 20; ++m) {
        const int k = wv * 320 + m * 16;
        float4 lo = *(const float4*)(W + wb + k);
        float4 hi = *(const float4*)(W + wb + k + 4);
        union { bf16x8 v; unsigned u[4]; } t_;
        t_.u[0] = PKBF(lo.x, lo.y); t_.u[1] = PKBF(lo.z, lo.w);
        t_.u[2] = PKBF(hi.x, hi.y); t_.u[3] = PKBF(hi.z, hi.w);
        bfr[m] = t_.v;
    }

    // ---- wait for this row-tile's batch selection ----
    if (!is_sel) {
        if (tid == 0) {
            while (__hip_atomic_load(&flags[xr], __ATOMIC_ACQUIRE,
                                     __HIP_MEMORY_SCOPE_AGENT) == 0)
                __builtin_amdgcn_s_sleep(8);
        }
        __syncthreads();
    }

    // ---- A fragment bases (per-lane gather) ----
    const int grow = row0 + frow;
    const int tt = __hip_atomic_load(&ws_times[grow], __ATOMIC_RELAXED,
                                     __HIP_MEMORY_SCOPE_AGENT);
    const size_t ah = ((size_t)xr * T_ + tt) * D_   + kq;
    const size_t ae = ((size_t)xr * T_ + tt) * DENT + kq;

    f32x16 acc = {0,0,0,0,0,0,0,0,0,0,0,0,0,0,0,0};
    #pragma unroll
    for (int m = 0; m < 20; ++m) {
        const int k = wv * 320 + m * 16;
        const float* src = (k < D_) ? (h_seq + ah + k) : (ent + ae + (k - D_));
        float4 lo = *(const float4*)(src);
        float4 hi = *(const float4*)(src + 4);
        union { bf16x8 v; unsigned u[4]; } t_;
        t_.u[0] = PKBF(lo.x, lo.y); t_.u[1] = PKBF(lo.z, lo.w);
        t_.u[2] = PKBF(hi.x, hi.y); t_.u[3] = PKBF(hi.z, hi.w);
        acc = __builtin_amdgcn_mfma_f32_32x32x16_bf16(t_.v, bfr[m], acc, 0, 0, 0);
    }

    // ---- scatter accumulator (C/D layout: col=lane&31, row=(r&3)+8*(r>>2)+4*(lane>>5)) ----
    #pragma unroll
    for (int r = 0; r < 16; ++r) {
        const int orow = (r & 3) + 8 * (r >> 2) + 4 * (lane >> 5);
        Red[wv][orow][frow] = acc[r];
    }
    __syncthreads();

    // ---- epilogue: sum 4 wave-partials, x valid, + bias + time_embed ----
    {
        const int rr = tid >> 3;            // 0..31
        const int c0 = (tid & 7) * 4;       // 0..28
        float4 s0 = *(const float4*)&Red[0][rr][c0];
        float4 s1 = *(const float4*)&Red[1][rr][c0];
        float4 s2 = *(const float4*)&Red[2][rr][c0];
        float4 s3 = *(const float4*)&Red[3][rr][c0];
        float4 s;
        s.x = (s0.x + s1.x) + (s2.x + s3.x);
        s.y = (s0.y + s1.y) + (s2.y + s3.y);
        s.z = (s0.z + s1.z) + (s2.z + s3.z);
        s.w = (s0.w + s1.w) + (s2.w + s3.w);
        const int og  = row0 + rr;
        const int cb  = col0 + c0;
        const int te_t = __hip_atomic_load(&ws_times[og], __ATOMIC_RELAXED,
                                           __HIP_MEMORY_SCOPE_AGENT);
        const float fv = (float)__hip_atomic_load(&ws_valid[og], __ATOMIC_RELAXED,
                                                  __HIP_MEMORY_SCOPE_AGENT);
        const int tcl = te_t < (TVOCAB - 1) ? te_t : (TVOCAB - 1);
        const float4 bi = *(const float4*)(bias + cb);
        const float4 te = *(const float4*)(temb + (size_t)tcl * D_ + cb);
        s.x = s.x * fv + bi.x + te.x;
        s.y = s.y * fv + bi.y + te.y;
        s.z = s.z * fv + bi.z + te.z;
        s.w = s.w * fv + bi.w + te.w;
        *(float4*)(out_tape + (size_t)og * D_ + cb) = s;
    }
}

// ---------------------------------------------------------------------------
extern "C" void kernel_launch(void* const* d_in, const int* in_sizes, int n_in,
                              void* d_out, int out_size, void* d_ws, size_t ws_size,
                              hipStream_t stream)
{
    const float* h_seq = (const float*)d_in[0];
    const float* z     = (const float*)d_in[1];
    const float* ent   = (const float*)d_in[2];
    const float* W     = (const float*)d_in[3];
    const float* bias  = (const float*)d_in[4];
    const float* temb  = (const float*)d_in[5];

    float* out       = (float*)d_out;
    float* out_tape  = out;                                // 262144
    float* out_valid = out + (size_t)B_ * E_ * D_;         // 256
    float* out_times = out_valid + B_ * E_;                // 256

    // ws layout: [0] times (256 int) | [1KB] valid (256 int) | [2KB] flags (8 int)
    int* ws_times = (int*)d_ws;
    int* ws_valid = (int*)((char*)d_ws + 1024);
    int* flags    = (int*)((char*)d_ws + 2048);

    hipMemsetAsync((char*)d_ws + 2048, 0, 32, stream);     // zero flags each call

    k_fused<<<256, 256, 0, stream>>>(h_seq, z, ent, W, bias, temb,
                                     ws_times, ws_valid, flags,
                                     out_tape, out_valid, out_times);
}

// Round 11
// 21.822 us; speedup vs baseline: 1.7829x; 1.7829x over previous
//
#include <hip/hip_runtime.h>
#include <hip/hip_bf16.h>

// Problem constants (from reference setup_inputs)
#define B_   8
#define T_   4096
#define D_   1024
#define DENT 256
#define F_   1280          // D_ + DENT
#define E_   32            // MAX_EVENTS
#define TVOCAB 512
#define THRB 0x40000000u   // __float_as_uint(2.0f)

typedef short  bf16x8 __attribute__((ext_vector_type(8)));
typedef float  f32x16 __attribute__((ext_vector_type(16)));

// RNE f32 pair -> packed bf16x2 (proven numerics, rounds 9/10)
#define PKBF(x, y) \
    ( ((__float_as_uint(x) + 0x7FFFu + ((__float_as_uint(x) >> 16) & 1u)) >> 16) | \
      ((__float_as_uint(y) + 0x7FFFu + ((__float_as_uint(y) >> 16) & 1u)) & 0xFFFF0000u) )

#define BK   128
#define LDPB 136           // bf16 row pitch: 272B, 16B-aligned
#define NIT  (F_ / BK)     // 10

// ---------------------------------------------------------------------------
// ONE kernel, 256 blocks x 256 threads, no inter-block communication.
// Every block redundantly runs event selection for its batch (xr) -> LDS,
// then the proven R9 MFMA GEMM (coalesced LDS staging, BK=128, 2-deep reg
// prefetch). W-tiles for k=0/1 are loaded BEFORE select (select-independent)
// so their latency hides under the select phase. yc==0 blocks also write
// out_valid/out_times. No workspace, no atomics across blocks, no memset.
// ---------------------------------------------------------------------------
__global__ __launch_bounds__(256) void k_all(
    const float* __restrict__ h_seq, const float* __restrict__ z,
    const float* __restrict__ ent,  const float* __restrict__ W,
    const float* __restrict__ bias, const float* __restrict__ temb,
    float* __restrict__ out_tape, float* __restrict__ out_valid,
    float* __restrict__ out_times)
{
    __shared__ unsigned short As[32][LDPB];
    __shared__ unsigned short Bs[32][LDPB];
    __shared__ float Red[4][32][36];        // cross-wave k-reduction
    __shared__ unsigned s_hist[4 * 257];    // per-wave private histograms
    __shared__ unsigned s_tot[256];
    __shared__ int s_cnt, s_nsel, s_bbin, s_prev;
    __shared__ unsigned s_bcg;
    __shared__ int s_selt[E_], s_sorted[E_], s_red[4];
    __shared__ int   s_times[E_];
    __shared__ float s_validf[E_];

    const int tid   = threadIdx.x;
    const int flat  = blockIdx.x;           // 0..255
    const int xcd   = flat & 7;
    const int ib    = flat >> 3;
    const int combo = xcd * 32 + ib;        // bijective 0..255
    const int yc    = combo >> 3;           // col tile 0..31
    const int xr    = combo & 7;            // row tile == batch 0..7
    const int row0  = xr * 32, col0 = yc * 32;
    const int lane  = tid & 63;
    const int wid   = tid >> 6;             // wave 0..3

    // ---- loader geometry (coalesced, R9-identical) ----
    const int lrow = tid >> 3;              // 0..31 (A row / B col in tile)
    const int lfo  = (tid & 7) * 4;         // 0..28
    const size_t b_base = (size_t)(col0 + lrow) * F_ + lfo;

    // ---- hoist W tiles 0/1 (select-independent; latency hides under select)
    float4 ra0[4], rb0[4], ra1[4], rb1[4];
    #pragma unroll
    for (int j = 0; j < 4; ++j) {
        rb0[j] = *(const float4*)(W + b_base + 0 * BK + j * 32);
        rb1[j] = *(const float4*)(W + b_base + 1 * BK + j * 32);
    }

    // ======================= SELECT (every block, batch xr) ================
    if (tid == 0) { s_cnt = 0; s_nsel = 0; }
    __syncthreads();

    unsigned key[16];
    {
        int cnt = 0;
        const float* zb = z + (size_t)xr * T_ * 8;
        #pragma unroll
        for (int j = 0; j < 16; ++j) {
            const int t = tid + j * 256;
            const float* zp = zb + (size_t)t * 8;
            float4 z0 = *(const float4*)(zp);
            float4 z1 = *(const float4*)(zp + 4);
            float m = fmaxf(fmaxf(fmaxf(fabsf(z0.x), fabsf(z0.y)),
                                  fmaxf(fabsf(z0.z), fabsf(z0.w))),
                            fmaxf(fmaxf(fabsf(z1.x), fabsf(z1.y)),
                                  fmaxf(fabsf(z1.z), fabsf(z1.w))));
            key[j] = __float_as_uint(m);
            if (key[j] > THRB) cnt++;
        }
        #pragma unroll
        for (int off = 32; off > 0; off >>= 1) cnt += __shfl_down(cnt, off);
        if (lane == 0) atomicAdd(&s_cnt, cnt);
    }
    __syncthreads();

    const int  n_ev = s_cnt;
    const bool fb   = (n_ev < 4);
    const int  V    = fb ? E_ : (n_ev < E_ ? n_ev : E_);

    if (!fb && n_ev <= E_) {
        #pragma unroll
        for (int j = 0; j < 16; ++j)
            if (key[j] > THRB) { int p = atomicAdd(&s_nsel, 1); s_selt[p] = tid + j * 256; }
        __syncthreads();
    } else {
        unsigned prefix = 0;
        int need = E_;
        for (int p = 0; p < 4; ++p) {
            const int shift = 24 - 8 * p;
            for (int i = tid; i < 4 * 257; i += 256) s_hist[i] = 0;
            __syncthreads();
            unsigned* h = s_hist + wid * 257;
            #pragma unroll
            for (int j = 0; j < 16; ++j) {
                bool elig = fb || (key[j] > THRB);
                if (elig && (p == 0 || (key[j] >> (shift + 8)) == prefix))
                    atomicAdd(&h[(key[j] >> shift) & 255u], 1u);
            }
            __syncthreads();
            {
                unsigned s = s_hist[tid] + s_hist[257 + tid]
                           + s_hist[2 * 257 + tid] + s_hist[3 * 257 + tid];
                s_tot[tid] = s;
            }
            __syncthreads();
            if (tid < 64) {
                unsigned b0 = s_tot[4*tid+0], b1 = s_tot[4*tid+1];
                unsigned b2 = s_tot[4*tid+2], b3 = s_tot[4*tid+3];
                unsigned lsum = b0 + b1 + b2 + b3;
                unsigned suf = lsum;                    // inclusive suffix
                #pragma unroll
                for (int off = 1; off < 64; off <<= 1) {
                    unsigned o = __shfl_down(suf, off);
                    if (tid + off < 64) suf += o;
                }
                unsigned excl = suf - lsum;
                unsigned cg3 = excl;
                unsigned cg2 = cg3 + b3;
                unsigned cg1 = cg2 + b2;
                unsigned cg0 = cg1 + b1;
                unsigned un  = (unsigned)need;
                if (cg3 < un && cg3 + b3 >= un) { s_bbin = 4*tid+3; s_bcg = cg3; }
                if (cg2 < un && cg2 + b2 >= un) { s_bbin = 4*tid+2; s_bcg = cg2; }
                if (cg1 < un && cg1 + b1 >= un) { s_bbin = 4*tid+1; s_bcg = cg1; }
                if (cg0 < un && cg0 + b0 >= un) { s_bbin = 4*tid+0; s_bcg = cg0; }
            }
            __syncthreads();
            need  -= (int)s_bcg;
            prefix = (prefix << 8) | (unsigned)s_bbin;
            __syncthreads();
        }
        const unsigned vstar   = prefix;
        const int      need_eq = need;

        #pragma unroll
        for (int j = 0; j < 16; ++j) {
            bool elig = fb || (key[j] > THRB);
            if (elig && key[j] > vstar) { int p = atomicAdd(&s_nsel, 1); s_selt[p] = tid + j * 256; }
        }
        __syncthreads();
        int prev = -1;
        const int base = s_nsel;
        for (int q = 0; q < need_eq; ++q) {
            int best = 0x7fffffff;
            #pragma unroll
            for (int j = 0; j < 16; ++j) {
                bool elig = fb || (key[j] > THRB);
                int  t    = tid + j * 256;
                if (elig && key[j] == vstar && t > prev && t < best) best = t;
            }
            #pragma unroll
            for (int off = 32; off > 0; off >>= 1) {
                int o = __shfl_down(best, off);
                if (o < best) best = o;
            }
            if (lane == 0) s_red[wid] = best;
            __syncthreads();
            if (tid == 0) {
                int m = s_red[0];
                #pragma unroll
                for (int w = 1; w < 4; ++w) if (s_red[w] < m) m = s_red[w];
                s_selt[base + q] = m;
                s_prev = m;
            }
            __syncthreads();
            prev = s_prev;
        }
    }

    // rank-sort ascending by time (distinct times -> deterministic)
    if (tid < V) {
        int ti = s_selt[tid];
        int rank = 0;
        for (int j = 0; j < V; ++j) rank += (s_selt[j] < ti);
        s_sorted[rank] = ti;
    }
    __syncthreads();
    if (tid < E_) {
        int valid = (tid < V) ? 1 : 0;
        int t     = valid ? s_sorted[tid] : 0;
        s_times[tid]  = t;
        s_validf[tid] = (float)valid;
        if (yc == 0) {
            out_times[xr * E_ + tid] = (float)t;
            out_valid[xr * E_ + tid] = (float)valid;
        }
    }
    __syncthreads();

    // ========================= GEMM (R9-proven) ===========================
    size_t a_baseh, a_basee;
    float  a_v;
    {
        int t   = s_times[lrow];
        a_v     = s_validf[lrow];
        a_baseh = ((size_t)xr * T_ + t) * D_   + lfo;
        a_basee = ((size_t)xr * T_ + t) * DENT + lfo;
    }

    const int wv   = tid >> 6;   // wave -> k-slice [wv*32, +32) per BK tile
    const int frow = lane & 31;
    const int kq   = (lane >> 5) * 8;

    f32x16 acc = {0,0,0,0,0,0,0,0,0,0,0,0,0,0,0,0};

#define LOAD_A(KC, RA) do {                                                  \
    const int fb0 = (KC) * BK;                                               \
    const float* asrc; size_t abase;                                         \
    if (fb0 < D_) { asrc = h_seq; abase = a_baseh + fb0; }                   \
    else          { asrc = ent;   abase = a_basee + (fb0 - D_); }            \
    _Pragma("unroll")                                                        \
    for (int j = 0; j < 4; ++j) RA[j] = *(const float4*)(asrc + abase + j * 32); \
} while (0)

#define LOAD_B(KC, RB) do {                                                  \
    const int fb0 = (KC) * BK;                                               \
    _Pragma("unroll")                                                        \
    for (int j = 0; j < 4; ++j) RB[j] = *(const float4*)(W + b_base + fb0 + j * 32); \
} while (0)

#define STORE_TILE(RA, RB) do {                                              \
    _Pragma("unroll")                                                        \
    for (int j = 0; j < 4; ++j) {                                            \
        float4 av = RA[j];                                                   \
        av.x *= a_v; av.y *= a_v; av.z *= a_v; av.w *= a_v;                  \
        *(uint2*)&As[lrow][lfo + j * 32] =                                   \
            make_uint2(PKBF(av.x, av.y), PKBF(av.z, av.w));                  \
        float4 bv = RB[j];                                                   \
        *(uint2*)&Bs[lrow][lfo + j * 32] =                                   \
            make_uint2(PKBF(bv.x, bv.y), PKBF(bv.z, bv.w));                  \
    } } while (0)

#define COMPUTE() do {                                                       \
    const int ks0 = wv * 32;                                                 \
    bf16x8 af0 = *(const bf16x8*)&As[frow][ks0 + kq];                        \
    bf16x8 bf0 = *(const bf16x8*)&Bs[frow][ks0 + kq];                        \
    acc = __builtin_amdgcn_mfma_f32_32x32x16_bf16(af0, bf0, acc, 0, 0, 0);   \
    bf16x8 af1 = *(const bf16x8*)&As[frow][ks0 + 16 + kq];                   \
    bf16x8 bf1 = *(const bf16x8*)&Bs[frow][ks0 + 16 + kq];                   \
    acc = __builtin_amdgcn_mfma_f32_32x32x16_bf16(af1, bf1, acc, 0, 0, 0);   \
} while (0)

    LOAD_A(0, ra0);
    LOAD_A(1, ra1);

    #pragma unroll
    for (int kc2 = 0; kc2 < NIT; kc2 += 2) {
        __syncthreads();
        STORE_TILE(ra0, rb0);
        __syncthreads();
        if (kc2 + 2 < NIT) { LOAD_A(kc2 + 2, ra0); LOAD_B(kc2 + 2, rb0); }
        COMPUTE();
        __syncthreads();
        STORE_TILE(ra1, rb1);
        __syncthreads();
        if (kc2 + 3 < NIT) { LOAD_A(kc2 + 3, ra1); LOAD_B(kc2 + 3, rb1); }
        COMPUTE();
    }
#undef LOAD_A
#undef LOAD_B
#undef STORE_TILE
#undef COMPUTE

    // ---- scatter accumulator (C/D: col=lane&31, row=(r&3)+8*(r>>2)+4*(lane>>5))
    __syncthreads();
    #pragma unroll
    for (int r = 0; r < 16; ++r) {
        const int orow = (r & 3) + 8 * (r >> 2) + 4 * (lane >> 5);
        Red[wv][orow][frow] = acc[r];
    }
    __syncthreads();

    // ---- epilogue: sum 4 wave-partials + bias + time_embed, f4 store ----
    {
        const int rr = tid >> 3;            // 0..31
        const int c0 = (tid & 7) * 4;       // 0..28
        float4 s0 = *(const float4*)&Red[0][rr][c0];
        float4 s1 = *(const float4*)&Red[1][rr][c0];
        float4 s2 = *(const float4*)&Red[2][rr][c0];
        float4 s3 = *(const float4*)&Red[3][rr][c0];
        float4 s;
        s.x = (s0.x + s1.x) + (s2.x + s3.x);
        s.y = (s0.y + s1.y) + (s2.y + s3.y);
        s.z = (s0.z + s1.z) + (s2.z + s3.z);
        s.w = (s0.w + s1.w) + (s2.w + s3.w);
        const int og = row0 + rr;
        const int cb = col0 + c0;
        const int t  = s_times[rr];
        const int tcl = t < (TVOCAB - 1) ? t : (TVOCAB - 1);
        const float4 bi = *(const float4*)(bias + cb);
        const float4 te = *(const float4*)(temb + (size_t)tcl * D_ + cb);
        s.x += bi.x + te.x; s.y += bi.y + te.y;
        s.z += bi.z + te.z; s.w += bi.w + te.w;
        *(float4*)(out_tape + (size_t)og * D_ + cb) = s;
    }
}

// ---------------------------------------------------------------------------
extern "C" void kernel_launch(void* const* d_in, const int* in_sizes, int n_in,
                              void* d_out, int out_size, void* d_ws, size_t ws_size,
                              hipStream_t stream)
{
    const float* h_seq = (const float*)d_in[0];
    const float* z     = (const float*)d_in[1];
    const float* ent   = (const float*)d_in[2];
    const float* W     = (const float*)d_in[3];
    const float* bias  = (const float*)d_in[4];
    const float* temb  = (const float*)d_in[5];

    float* out       = (float*)d_out;
    float* out_tape  = out;                                // 262144
    float* out_valid = out + (size_t)B_ * E_ * D_;         // 256
    float* out_times = out_valid + B_ * E_;                // 256

    k_all<<<256, 256, 0, stream>>>(h_seq, z, ent, W, bias, temb,
                                   out_tape, out_valid, out_times);
}

// Round 12
// 18.388 us; speedup vs baseline: 2.1158x; 1.1867x over previous
//
#include <hip/hip_runtime.h>
#include <hip/hip_bf16.h>

// Problem constants (from reference setup_inputs)
#define B_   8
#define T_   4096
#define D_   1024
#define DENT 256
#define F_   1280          // D_ + DENT
#define E_   32            // MAX_EVENTS
#define TVOCAB 512
#define THRB 0x40000000u   // __float_as_uint(2.0f)

typedef short  bf16x8 __attribute__((ext_vector_type(8)));
typedef float  f32x16 __attribute__((ext_vector_type(16)));

#define BK   128
#define LDPB 136           // bf16 row pitch (shorts): 272B, 16B-aligned
#define NIT  (F_ / BK)     // 10

// RNE f32 pair -> packed bf16x2 via HW cvt (compiler emits v_cvt_pk_bf16_f32;
// numerically identical to the manual RNE pack used in rounds 9-11)
__device__ __forceinline__ unsigned pk2(float x, float y) {
    __hip_bfloat162 h2;
    h2.x = __float2bfloat16(x);
    h2.y = __float2bfloat16(y);
    return *reinterpret_cast<unsigned*>(&h2);
}

// ---------------------------------------------------------------------------
// ONE kernel, 256 blocks x 256 threads (R11 skeleton).
// Select: 2 radix passes (16-bit pivot prefix) + parallel rank-select of the
// boundary bin (exact lax.top_k tie semantics); falls back to passes 3/4 +
// iterative tie loop if the boundary bin exceeds 256 members (block-uniform).
// GEMM: bf16 MFMA, LDS double-buffered (1 barrier/tile), cvt_pk staging,
// cross-wave K-reduce with Red aliased over the dead LDS buffers.
// ---------------------------------------------------------------------------
__global__ __launch_bounds__(256) void k_all(
    const float* __restrict__ h_seq, const float* __restrict__ z,
    const float* __restrict__ ent,  const float* __restrict__ W,
    const float* __restrict__ bias, const float* __restrict__ temb,
    float* __restrict__ out_tape, float* __restrict__ out_valid,
    float* __restrict__ out_times)
{
    // 4 x 8704B = 34816B: As0|Bs0|As1|Bs1 ; Red (18432B) aliases the front
    __shared__ __align__(16) char smem_raw[34816];
    typedef unsigned short ldsrow_t[LDPB];
    ldsrow_t* As0 = (ldsrow_t*)(smem_raw);
    ldsrow_t* Bs0 = (ldsrow_t*)(smem_raw + 8704);
    ldsrow_t* As1 = (ldsrow_t*)(smem_raw + 17408);
    ldsrow_t* Bs1 = (ldsrow_t*)(smem_raw + 26112);
    float (*Red)[32][36] = (float (*)[32][36])smem_raw;

    __shared__ unsigned s_hist[4 * 257];
    __shared__ unsigned s_tot[256];
    __shared__ unsigned long long s_list[256];
    __shared__ int s_cnt, s_nsel, s_ntie, s_bbin, s_prev;
    __shared__ unsigned s_bcg;
    __shared__ int s_selt[E_], s_sorted[E_], s_red[4];
    __shared__ int   s_times[E_];
    __shared__ float s_validf[E_];

    const int tid   = threadIdx.x;
    const int flat  = blockIdx.x;           // 0..255
    const int xcd   = flat & 7;
    const int ib    = flat >> 3;
    const int combo = xcd * 32 + ib;        // bijective 0..255
    const int yc    = combo >> 3;           // col tile 0..31
    const int xr    = combo & 7;            // row tile == batch 0..7
    const int row0  = xr * 32, col0 = yc * 32;
    const int lane  = tid & 63;
    const int wid   = tid >> 6;             // wave 0..3

    // ---- loader geometry (coalesced) ----
    const int lrow = tid >> 3;              // 0..31 (A row / B col in tile)
    const int lfo  = (tid & 7) * 4;         // 0..28
    const size_t b_base = (size_t)(col0 + lrow) * F_ + lfo;

    // ---- hoist W tiles 0/1 (select-independent; latency hides under select)
    float4 ra0[4], rb0[4], ra1[4], rb1[4];
    #pragma unroll
    for (int j = 0; j < 4; ++j) {
        rb0[j] = *(const float4*)(W + b_base + 0 * BK + j * 32);
        rb1[j] = *(const float4*)(W + b_base + 1 * BK + j * 32);
    }

    // ======================= SELECT (every block, batch xr) ================
    if (tid == 0) { s_cnt = 0; s_nsel = 0; s_ntie = 0; }
    __syncthreads();

    unsigned key[16];
    {
        int cnt = 0;
        const float* zb = z + (size_t)xr * T_ * 8;
        #pragma unroll
        for (int j = 0; j < 16; ++j) {
            const int t = tid + j * 256;
            const float* zp = zb + (size_t)t * 8;
            float4 z0 = *(const float4*)(zp);
            float4 z1 = *(const float4*)(zp + 4);
            float m = fmaxf(fmaxf(fmaxf(fabsf(z0.x), fabsf(z0.y)),
                                  fmaxf(fabsf(z0.z), fabsf(z0.w))),
                            fmaxf(fmaxf(fabsf(z1.x), fabsf(z1.y)),
                                  fmaxf(fabsf(z1.z), fabsf(z1.w))));
            key[j] = __float_as_uint(m);
            if (key[j] > THRB) cnt++;
        }
        #pragma unroll
        for (int off = 32; off > 0; off >>= 1) cnt += __shfl_down(cnt, off);
        if (lane == 0) atomicAdd(&s_cnt, cnt);
    }
    __syncthreads();

    const int  n_ev = s_cnt;
    const bool fb   = (n_ev < 4);
    const int  V    = fb ? E_ : (n_ev < E_ ? n_ev : E_);

#define RADIX_PASS(P) do {                                                   \
    const int shift = 24 - 8 * (P);                                          \
    for (int i = tid; i < 4 * 257; i += 256) s_hist[i] = 0;                  \
    __syncthreads();                                                         \
    unsigned* h = s_hist + wid * 257;                                        \
    _Pragma("unroll")                                                        \
    for (int j = 0; j < 16; ++j) {                                           \
        bool elig = fb || (key[j] > THRB);                                   \
        if (elig && ((P) == 0 || (key[j] >> (shift + 8)) == prefix))         \
            atomicAdd(&h[(key[j] >> shift) & 255u], 1u);                     \
    }                                                                        \
    __syncthreads();                                                         \
    {                                                                        \
        unsigned s = s_hist[tid] + s_hist[257 + tid]                         \
                   + s_hist[2 * 257 + tid] + s_hist[3 * 257 + tid];          \
        s_tot[tid] = s;                                                      \
    }                                                                        \
    __syncthreads();                                                         \
    if (tid < 64) {                                                          \
        unsigned b0 = s_tot[4*tid+0], b1 = s_tot[4*tid+1];                   \
        unsigned b2 = s_tot[4*tid+2], b3 = s_tot[4*tid+3];                   \
        unsigned lsum = b0 + b1 + b2 + b3;                                   \
        unsigned suf = lsum;                                                 \
        _Pragma("unroll")                                                    \
        for (int off = 1; off < 64; off <<= 1) {                             \
            unsigned o = __shfl_down(suf, off);                              \
            if (tid + off < 64) suf += o;                                    \
        }                                                                    \
        unsigned excl = suf - lsum;                                          \
        unsigned cg3 = excl;                                                 \
        unsigned cg2 = cg3 + b3;                                             \
        unsigned cg1 = cg2 + b2;                                             \
        unsigned cg0 = cg1 + b1;                                             \
        unsigned un  = (unsigned)need;                                       \
        if (cg3 < un && cg3 + b3 >= un) { s_bbin = 4*tid+3; s_bcg = cg3; }   \
        if (cg2 < un && cg2 + b2 >= un) { s_bbin = 4*tid+2; s_bcg = cg2; }   \
        if (cg1 < un && cg1 + b1 >= un) { s_bbin = 4*tid+1; s_bcg = cg1; }   \
        if (cg0 < un && cg0 + b0 >= un) { s_bbin = 4*tid+0; s_bcg = cg0; }   \
    }                                                                        \
    __syncthreads();                                                         \
    need  -= (int)s_bcg;                                                     \
    prefix = (prefix << 8) | (unsigned)s_bbin;                               \
    __syncthreads();                                                         \
} while (0)

    if (!fb && n_ev <= E_) {
        #pragma unroll
        for (int j = 0; j < 16; ++j)
            if (key[j] > THRB) { int p = atomicAdd(&s_nsel, 1); s_selt[p] = tid + j * 256; }
        __syncthreads();
    } else {
        unsigned prefix = 0;
        int need = E_;
        RADIX_PASS(0);
        RADIX_PASS(1);
        const unsigned pre16 = prefix;      // 16-bit pivot prefix

        // collect strictly-greater (by 16-bit prefix) + boundary candidates
        #pragma unroll
        for (int j = 0; j < 16; ++j) {
            bool elig = fb || (key[j] > THRB);
            if (!elig) continue;
            unsigned k16 = key[j] >> 16;
            if (k16 > pre16) {
                int p = atomicAdd(&s_nsel, 1);
                s_selt[p] = tid + j * 256;
            } else if (k16 == pre16) {
                int p = atomicAdd(&s_ntie, 1);
                if (p < 256)
                    s_list[p] = ((unsigned long long)key[j] << 32)
                              | (unsigned)(0xFFFFFFFFu - (unsigned)(tid + j * 256));
            }
        }
        __syncthreads();
        const int cnt_b    = s_ntie;
        const int base     = s_nsel;
        const int need_rem = need;

        if (cnt_b <= 256) {
            // parallel rank-select: rank by (key desc, idx asc) via u64 compare
            if (tid < cnt_b) {
                unsigned long long me = s_list[tid];
                int rank = 0;
                for (int j = 0; j < cnt_b; ++j) rank += (s_list[j] > me);
                if (rank < need_rem)
                    s_selt[base + rank] =
                        (int)(0xFFFFFFFFu - (unsigned)(me & 0xFFFFFFFFull));
            }
            __syncthreads();
        } else {
            // fallback: refine 2 more passes + iterative tie loop (R11-proven)
            RADIX_PASS(2);
            RADIX_PASS(3);
            const unsigned vstar   = prefix;
            const int      need_eq = need;
            #pragma unroll
            for (int j = 0; j < 16; ++j) {
                bool elig = fb || (key[j] > THRB);
                unsigned k16 = key[j] >> 16;
                if (elig && k16 == pre16 && key[j] > vstar) {
                    int p = atomicAdd(&s_nsel, 1);
                    s_selt[p] = tid + j * 256;
                }
            }
            __syncthreads();
            int prev = -1;
            const int base2 = s_nsel;
            for (int q = 0; q < need_eq; ++q) {
                int best = 0x7fffffff;
                #pragma unroll
                for (int j = 0; j < 16; ++j) {
                    bool elig = fb || (key[j] > THRB);
                    int  t    = tid + j * 256;
                    if (elig && key[j] == vstar && t > prev && t < best) best = t;
                }
                #pragma unroll
                for (int off = 32; off > 0; off >>= 1) {
                    int o = __shfl_down(best, off);
                    if (o < best) best = o;
                }
                if (lane == 0) s_red[wid] = best;
                __syncthreads();
                if (tid == 0) {
                    int m = s_red[0];
                    #pragma unroll
                    for (int w = 1; w < 4; ++w) if (s_red[w] < m) m = s_red[w];
                    s_selt[base2 + q] = m;
                    s_prev = m;
                }
                __syncthreads();
                prev = s_prev;
            }
        }
    }
#undef RADIX_PASS

    // rank-sort ascending by time (distinct times -> deterministic)
    if (tid < V) {
        int ti = s_selt[tid];
        int rank = 0;
        for (int j = 0; j < V; ++j) rank += (s_selt[j] < ti);
        s_sorted[rank] = ti;
    }
    __syncthreads();
    if (tid < E_) {
        int valid = (tid < V) ? 1 : 0;
        int t     = valid ? s_sorted[tid] : 0;
        s_times[tid]  = t;
        s_validf[tid] = (float)valid;
        if (yc == 0) {
            out_times[xr * E_ + tid] = (float)t;
            out_valid[xr * E_ + tid] = (float)valid;
        }
    }
    __syncthreads();

    // ========================= GEMM (dbuf MFMA) ===========================
    size_t a_baseh, a_basee;
    float  a_v;
    {
        int t   = s_times[lrow];
        a_v     = s_validf[lrow];
        a_baseh = ((size_t)xr * T_ + t) * D_   + lfo;
        a_basee = ((size_t)xr * T_ + t) * DENT + lfo;
    }

    const int wv   = tid >> 6;   // wave -> k-slice [wv*32, +32) per BK tile
    const int frow = lane & 31;
    const int kq   = (lane >> 5) * 8;

    f32x16 acc = {0,0,0,0,0,0,0,0,0,0,0,0,0,0,0,0};

#define LOAD_A(KC, RA) do {                                                  \
    const int fb0 = (KC) * BK;                                               \
    const float* asrc; size_t abase;                                         \
    if (fb0 < D_) { asrc = h_seq; abase = a_baseh + fb0; }                   \
    else          { asrc = ent;   abase = a_basee + (fb0 - D_); }            \
    _Pragma("unroll")                                                        \
    for (int j = 0; j < 4; ++j) RA[j] = *(const float4*)(asrc + abase + j * 32); \
} while (0)

#define LOAD_B(KC, RB) do {                                                  \
    const int fb0 = (KC) * BK;                                               \
    _Pragma("unroll")                                                        \
    for (int j = 0; j < 4; ++j) RB[j] = *(const float4*)(W + b_base + fb0 + j * 32); \
} while (0)

#define STORE_T(AS, BS, RA, RB) do {                                         \
    _Pragma("unroll")                                                        \
    for (int j = 0; j < 4; ++j) {                                            \
        float4 av = RA[j];                                                   \
        *(uint2*)&AS[lrow][lfo + j * 32] =                                   \
            make_uint2(pk2(av.x * a_v, av.y * a_v),                          \
                       pk2(av.z * a_v, av.w * a_v));                         \
        float4 bv = RB[j];                                                   \
        *(uint2*)&BS[lrow][lfo + j * 32] =                                   \
            make_uint2(pk2(bv.x, bv.y), pk2(bv.z, bv.w));                    \
    } } while (0)

#define COMPUTE(AS, BS) do {                                                 \
    const int ks0 = wv * 32;                                                 \
    bf16x8 af0 = *(const bf16x8*)&AS[frow][ks0 + kq];                        \
    bf16x8 bf0 = *(const bf16x8*)&BS[frow][ks0 + kq];                        \
    acc = __builtin_amdgcn_mfma_f32_32x32x16_bf16(af0, bf0, acc, 0, 0, 0);   \
    bf16x8 af1 = *(const bf16x8*)&AS[frow][ks0 + 16 + kq];                   \
    bf16x8 bf1 = *(const bf16x8*)&BS[frow][ks0 + 16 + kq];                   \
    acc = __builtin_amdgcn_mfma_f32_32x32x16_bf16(af1, bf1, acc, 0, 0, 0);   \
} while (0)

    LOAD_A(0, ra0);
    LOAD_A(1, ra1);
    STORE_T(As0, Bs0, ra0, rb0);
    __syncthreads();

    #pragma unroll
    for (int k = 0; k < NIT; ++k) {
        const int p = k & 1;
        if (k + 1 < NIT) {
            if (p == 0) STORE_T(As1, Bs1, ra1, rb1);
            else        STORE_T(As0, Bs0, ra0, rb0);
        }
        if (k + 2 < NIT) {
            if (p == 0) { LOAD_A(k + 2, ra0); LOAD_B(k + 2, rb0); }
            else        { LOAD_A(k + 2, ra1); LOAD_B(k + 2, rb1); }
        }
        if (p == 0) COMPUTE(As0, Bs0);
        else        COMPUTE(As1, Bs1);
        __syncthreads();
    }
#undef LOAD_A
#undef LOAD_B
#undef STORE_T
#undef COMPUTE

    // ---- scatter accumulator into Red (aliases dead As/Bs buffers) ----
    // (final loop barrier above guarantees all LDS reads are done)
    #pragma unroll
    for (int r = 0; r < 16; ++r) {
        const int orow = (r & 3) + 8 * (r >> 2) + 4 * (lane >> 5);
        Red[wv][orow][frow] = acc[r];
    }
    __syncthreads();

    // ---- epilogue: sum 4 wave-partials + bias + time_embed, f4 store ----
    {
        const int rr = tid >> 3;            // 0..31
        const int c0 = (tid & 7) * 4;       // 0..28
        float4 s0 = *(const float4*)&Red[0][rr][c0];
        float4 s1 = *(const float4*)&Red[1][rr][c0];
        float4 s2 = *(const float4*)&Red[2][rr][c0];
        float4 s3 = *(const float4*)&Red[3][rr][c0];
        float4 s;
        s.x = (s0.x + s1.x) + (s2.x + s3.x);
        s.y = (s0.y + s1.y) + (s2.y + s3.y);
        s.z = (s0.z + s1.z) + (s2.z + s3.z);
        s.w = (s0.w + s1.w) + (s2.w + s3.w);
        const int og = row0 + rr;
        const int cb = col0 + c0;
        const int t  = s_times[rr];
        const int tcl = t < (TVOCAB - 1) ? t : (TVOCAB - 1);
        const float4 bi = *(const float4*)(bias + cb);
        const float4 te = *(const float4*)(temb + (size_t)tcl * D_ + cb);
        s.x += bi.x + te.x; s.y += bi.y + te.y;
        s.z += bi.z + te.z; s.w += bi.w + te.w;
        *(float4*)(out_tape + (size_t)og * D_ + cb) = s;
    }
}

// ---------------------------------------------------------------------------
extern "C" void kernel_launch(void* const* d_in, const int* in_sizes, int n_in,
                              void* d_out, int out_size, void* d_ws, size_t ws_size,
                              hipStream_t stream)
{
    const float* h_seq = (const float*)d_in[0];
    const float* z     = (const float*)d_in[1];
    const float* ent   = (const float*)d_in[2];
    const float* W     = (const float*)d_in[3];
    const float* bias  = (const float*)d_in[4];
    const float* temb  = (const float*)d_in[5];

    float* out       = (float*)d_out;
    float* out_tape  = out;                                // 262144
    float* out_valid = out + (size_t)B_ * E_ * D_;         // 256
    float* out_times = out_valid + B_ * E_;                // 256

    k_all<<<256, 256, 0, stream>>>(h_seq, z, ent, W, bias, temb,
                                   out_tape, out_valid, out_times);
}

// Round 13
// 18.289 us; speedup vs baseline: 2.1273x; 1.0054x over previous
//
#include <hip/hip_runtime.h>
#include <hip/hip_bf16.h>

// Problem constants (from reference setup_inputs)
#define B_   8
#define T_   4096
#define D_   1024
#define DENT 256
#define F_   1280          // D_ + DENT
#define E_   32            // MAX_EVENTS
#define TVOCAB 512
#define THRB 0x40000000u   // __float_as_uint(2.0f)

typedef short  bf16x8 __attribute__((ext_vector_type(8)));
typedef float  f32x16 __attribute__((ext_vector_type(16)));

#define BK   128
#define LDPB 136           // bf16 row pitch (shorts): 272B, 16B-aligned
#define NIT  (F_ / BK)     // 10

// RNE f32 pair -> packed bf16x2 via HW cvt (v_cvt_pk_bf16_f32)
__device__ __forceinline__ unsigned pk2(float x, float y) {
    __hip_bfloat162 h2;
    h2.x = __float2bfloat16(x);
    h2.y = __float2bfloat16(y);
    return *reinterpret_cast<unsigned*>(&h2);
}

// ---------------------------------------------------------------------------
// ONE kernel, 256 blocks x 256 threads (R12 skeleton).
// R13: (1) B tiles 0/1 staged into LDS BEFORE select (latency hidden there);
//      (2) radix pass merges wave-histograms inside the 64-thread scan
//          (one less barrier per pass);
//      (3) trailing radix barrier folded into next pass's zeroing barrier.
// ---------------------------------------------------------------------------
__global__ __launch_bounds__(256) void k_all(
    const float* __restrict__ h_seq, const float* __restrict__ z,
    const float* __restrict__ ent,  const float* __restrict__ W,
    const float* __restrict__ bias, const float* __restrict__ temb,
    float* __restrict__ out_tape, float* __restrict__ out_valid,
    float* __restrict__ out_times)
{
    // 4 x 8704B = 34816B: As0|Bs0|As1|Bs1 ; Red (18432B) aliases As0/Bs0/As1
    __shared__ __align__(16) char smem_raw[34816];
    typedef unsigned short ldsrow_t[LDPB];
    ldsrow_t* As0 = (ldsrow_t*)(smem_raw);
    ldsrow_t* Bs0 = (ldsrow_t*)(smem_raw + 8704);
    ldsrow_t* As1 = (ldsrow_t*)(smem_raw + 17408);
    ldsrow_t* Bs1 = (ldsrow_t*)(smem_raw + 26112);
    float (*Red)[32][36] = (float (*)[32][36])smem_raw;

    __shared__ unsigned s_hist[4 * 257];
    __shared__ unsigned long long s_list[256];
    __shared__ int s_cnt, s_nsel, s_ntie, s_bbin, s_prev;
    __shared__ unsigned s_bcg;
    __shared__ int s_selt[E_], s_sorted[E_], s_red[4];
    __shared__ int   s_times[E_];
    __shared__ float s_validf[E_];

    const int tid   = threadIdx.x;
    const int flat  = blockIdx.x;           // 0..255
    const int xcd   = flat & 7;
    const int ib    = flat >> 3;
    const int combo = xcd * 32 + ib;        // bijective 0..255
    const int yc    = combo >> 3;           // col tile 0..31
    const int xr    = combo & 7;            // row tile == batch 0..7
    const int row0  = xr * 32, col0 = yc * 32;
    const int lane  = tid & 63;
    const int wid   = tid >> 6;             // wave 0..3

    // ---- loader geometry (coalesced) ----
    const int lrow = tid >> 3;              // 0..31 (A row / B col in tile)
    const int lfo  = (tid & 7) * 4;         // 0..28
    const size_t b_base = (size_t)(col0 + lrow) * F_ + lfo;

#define LOAD_B(KC, RB) do {                                                  \
    const int fb0 = (KC) * BK;                                               \
    _Pragma("unroll")                                                        \
    for (int j = 0; j < 4; ++j) RB[j] = *(const float4*)(W + b_base + fb0 + j * 32); \
} while (0)

#define STORE_B(BS, RB) do {                                                 \
    _Pragma("unroll")                                                        \
    for (int j = 0; j < 4; ++j) {                                            \
        float4 bv = RB[j];                                                   \
        *(uint2*)&BS[lrow][lfo + j * 32] =                                   \
            make_uint2(pk2(bv.x, bv.y), pk2(bv.z, bv.w));                    \
    } } while (0)

    // ---- stage B tiles 0/1 into LDS BEFORE select (select-independent) ----
    {
        float4 rbt[4];
        LOAD_B(0, rbt);
        STORE_B(Bs0, rbt);
        LOAD_B(1, rbt);
        STORE_B(Bs1, rbt);
    }
    if (tid == 0) { s_cnt = 0; s_nsel = 0; s_ntie = 0; }
    // no barrier needed yet: each thread wrote disjoint LDS; first consumer
    // barrier below covers visibility.

    // ======================= SELECT (every block, batch xr) ================
    unsigned key[16];
    {
        int cnt = 0;
        const float* zb = z + (size_t)xr * T_ * 8;
        #pragma unroll
        for (int j = 0; j < 16; ++j) {
            const int t = tid + j * 256;
            const float* zp = zb + (size_t)t * 8;
            float4 z0 = *(const float4*)(zp);
            float4 z1 = *(const float4*)(zp + 4);
            float m = fmaxf(fmaxf(fmaxf(fabsf(z0.x), fabsf(z0.y)),
                                  fmaxf(fabsf(z0.z), fabsf(z0.w))),
                            fmaxf(fmaxf(fabsf(z1.x), fabsf(z1.y)),
                                  fmaxf(fabsf(z1.z), fabsf(z1.w))));
            key[j] = __float_as_uint(m);
            if (key[j] > THRB) cnt++;
        }
        #pragma unroll
        for (int off = 32; off > 0; off >>= 1) cnt += __shfl_down(cnt, off);
        if (lane == 0) atomicAdd(&s_cnt, cnt);
    }
    __syncthreads();

    const int  n_ev = s_cnt;
    const bool fb   = (n_ev < 4);
    const int  V    = fb ? E_ : (n_ev < E_ ? n_ev : E_);

    // radix pass: zero-hist(barrier) -> atomics(barrier) -> 64-thr merged
    // scan(barrier). prefix/need update is uniform (from s_bbin/s_bcg).
#define RADIX_PASS(P) do {                                                   \
    const int shift = 24 - 8 * (P);                                          \
    for (int i = tid; i < 4 * 257; i += 256) s_hist[i] = 0;                  \
    __syncthreads();                                                         \
    unsigned* h = s_hist + wid * 257;                                        \
    _Pragma("unroll")                                                        \
    for (int j = 0; j < 16; ++j) {                                           \
        bool elig = fb || (key[j] > THRB);                                   \
        if (elig && ((P) == 0 || (key[j] >> (shift + 8)) == prefix))         \
            atomicAdd(&h[(key[j] >> shift) & 255u], 1u);                     \
    }                                                                        \
    __syncthreads();                                                         \
    if (tid < 64) {                                                          \
        unsigned b0 = 0, b1 = 0, b2 = 0, b3 = 0;                             \
        _Pragma("unroll")                                                    \
        for (int w = 0; w < 4; ++w) {                                        \
            const unsigned* hw = s_hist + w * 257 + 4 * tid;                 \
            b0 += hw[0]; b1 += hw[1]; b2 += hw[2]; b3 += hw[3];              \
        }                                                                    \
        unsigned lsum = b0 + b1 + b2 + b3;                                   \
        unsigned suf = lsum;                                                 \
        _Pragma("unroll")                                                    \
        for (int off = 1; off < 64; off <<= 1) {                             \
            unsigned o = __shfl_down(suf, off);                              \
            if (tid + off < 64) suf += o;                                    \
        }                                                                    \
        unsigned excl = suf - lsum;                                          \
        unsigned cg3 = excl;                                                 \
        unsigned cg2 = cg3 + b3;                                             \
        unsigned cg1 = cg2 + b2;                                             \
        unsigned cg0 = cg1 + b1;                                             \
        unsigned un  = (unsigned)need;                                       \
        if (cg3 < un && cg3 + b3 >= un) { s_bbin = 4*tid+3; s_bcg = cg3; }   \
        if (cg2 < un && cg2 + b2 >= un) { s_bbin = 4*tid+2; s_bcg = cg2; }   \
        if (cg1 < un && cg1 + b1 >= un) { s_bbin = 4*tid+1; s_bcg = cg1; }   \
        if (cg0 < un && cg0 + b0 >= un) { s_bbin = 4*tid+0; s_bcg = cg0; }   \
    }                                                                        \
    __syncthreads();                                                         \
    need  -= (int)s_bcg;                                                     \
    prefix = (prefix << 8) | (unsigned)s_bbin;                               \
} while (0)

    if (!fb && n_ev <= E_) {
        #pragma unroll
        for (int j = 0; j < 16; ++j)
            if (key[j] > THRB) { int p = atomicAdd(&s_nsel, 1); s_selt[p] = tid + j * 256; }
        __syncthreads();
    } else {
        unsigned prefix = 0;
        int need = E_;
        RADIX_PASS(0);
        RADIX_PASS(1);
        const unsigned pre16 = prefix;      // 16-bit pivot prefix

        // collect strictly-greater (by 16-bit prefix) + boundary candidates
        #pragma unroll
        for (int j = 0; j < 16; ++j) {
            bool elig = fb || (key[j] > THRB);
            if (!elig) continue;
            unsigned k16 = key[j] >> 16;
            if (k16 > pre16) {
                int p = atomicAdd(&s_nsel, 1);
                s_selt[p] = tid + j * 256;
            } else if (k16 == pre16) {
                int p = atomicAdd(&s_ntie, 1);
                if (p < 256)
                    s_list[p] = ((unsigned long long)key[j] << 32)
                              | (unsigned)(0xFFFFFFFFu - (unsigned)(tid + j * 256));
            }
        }
        __syncthreads();
        const int cnt_b    = s_ntie;
        const int base     = s_nsel;
        const int need_rem = need;

        if (cnt_b <= 256) {
            // parallel rank-select: (key desc, idx asc) via u64 compare
            if (tid < cnt_b) {
                unsigned long long me = s_list[tid];
                int rank = 0;
                for (int j = 0; j < cnt_b; ++j) rank += (s_list[j] > me);
                if (rank < need_rem)
                    s_selt[base + rank] =
                        (int)(0xFFFFFFFFu - (unsigned)(me & 0xFFFFFFFFull));
            }
            __syncthreads();
        } else {
            // fallback: refine 2 more passes + iterative tie loop (proven)
            RADIX_PASS(2);
            RADIX_PASS(3);
            const unsigned vstar   = prefix;
            const int      need_eq = need;
            __syncthreads();
            #pragma unroll
            for (int j = 0; j < 16; ++j) {
                bool elig = fb || (key[j] > THRB);
                unsigned k16 = key[j] >> 16;
                if (elig && k16 == pre16 && key[j] > vstar) {
                    int p = atomicAdd(&s_nsel, 1);
                    s_selt[p] = tid + j * 256;
                }
            }
            __syncthreads();
            int prev = -1;
            const int base2 = s_nsel;
            for (int q = 0; q < need_eq; ++q) {
                int best = 0x7fffffff;
                #pragma unroll
                for (int j = 0; j < 16; ++j) {
                    bool elig = fb || (key[j] > THRB);
                    int  t    = tid + j * 256;
                    if (elig && key[j] == vstar && t > prev && t < best) best = t;
                }
                #pragma unroll
                for (int off = 32; off > 0; off >>= 1) {
                    int o = __shfl_down(best, off);
                    if (o < best) best = o;
                }
                if (lane == 0) s_red[wid] = best;
                __syncthreads();
                if (tid == 0) {
                    int m = s_red[0];
                    #pragma unroll
                    for (int w = 1; w < 4; ++w) if (s_red[w] < m) m = s_red[w];
                    s_selt[base2 + q] = m;
                    s_prev = m;
                }
                __syncthreads();
                prev = s_prev;
            }
        }
    }
#undef RADIX_PASS

    // rank-sort ascending by time (distinct times -> deterministic)
    if (tid < V) {
        int ti = s_selt[tid];
        int rank = 0;
        for (int j = 0; j < V; ++j) rank += (s_selt[j] < ti);
        s_sorted[rank] = ti;
    }
    __syncthreads();
    if (tid < E_) {
        int valid = (tid < V) ? 1 : 0;
        int t     = valid ? s_sorted[tid] : 0;
        s_times[tid]  = t;
        s_validf[tid] = (float)valid;
        if (yc == 0) {
            out_times[xr * E_ + tid] = (float)t;
            out_valid[xr * E_ + tid] = (float)valid;
        }
    }
    __syncthreads();

    // ========================= GEMM (dbuf MFMA) ===========================
    size_t a_baseh, a_basee;
    float  a_v;
    {
        int t   = s_times[lrow];
        a_v     = s_validf[lrow];
        a_baseh = ((size_t)xr * T_ + t) * D_   + lfo;
        a_basee = ((size_t)xr * T_ + t) * DENT + lfo;
    }

    const int wv   = tid >> 6;   // wave -> k-slice [wv*32, +32) per BK tile
    const int frow = lane & 31;
    const int kq   = (lane >> 5) * 8;

    float4 ra0[4], rb0[4], ra1[4], rb1[4];
    f32x16 acc = {0,0,0,0,0,0,0,0,0,0,0,0,0,0,0,0};

#define LOAD_A(KC, RA) do {                                                  \
    const int fb0 = (KC) * BK;                                               \
    const float* asrc; size_t abase;                                         \
    if (fb0 < D_) { asrc = h_seq; abase = a_baseh + fb0; }                   \
    else          { asrc = ent;   abase = a_basee + (fb0 - D_); }            \
    _Pragma("unroll")                                                        \
    for (int j = 0; j < 4; ++j) RA[j] = *(const float4*)(asrc + abase + j * 32); \
} while (0)

#define STORE_A(AS, RA) do {                                                 \
    _Pragma("unroll")                                                        \
    for (int j = 0; j < 4; ++j) {                                            \
        float4 av = RA[j];                                                   \
        *(uint2*)&AS[lrow][lfo + j * 32] =                                   \
            make_uint2(pk2(av.x * a_v, av.y * a_v),                          \
                       pk2(av.z * a_v, av.w * a_v));                         \
    } } while (0)

#define COMPUTE(AS, BS) do {                                                 \
    const int ks0 = wv * 32;                                                 \
    bf16x8 af0 = *(const bf16x8*)&AS[frow][ks0 + kq];                        \
    bf16x8 bf0 = *(const bf16x8*)&BS[frow][ks0 + kq];                        \
    acc = __builtin_amdgcn_mfma_f32_32x32x16_bf16(af0, bf0, acc, 0, 0, 0);   \
    bf16x8 af1 = *(const bf16x8*)&AS[frow][ks0 + 16 + kq];                   \
    bf16x8 bf1 = *(const bf16x8*)&BS[frow][ks0 + 16 + kq];                   \
    acc = __builtin_amdgcn_mfma_f32_32x32x16_bf16(af1, bf1, acc, 0, 0, 0);   \
} while (0)

    // prologue: A for tiles 0/1 (B already in LDS from pre-select staging)
    LOAD_A(0, ra0);
    LOAD_A(1, ra1);
    STORE_A(As0, ra0);
    __syncthreads();

    #pragma unroll
    for (int k = 0; k < NIT; ++k) {
        const int p = k & 1;
        if (k + 1 < NIT) {
            if (p == 0) { STORE_A(As1, ra1); if (k + 1 >= 2) STORE_B(Bs1, rb1); }
            else        { STORE_A(As0, ra0); STORE_B(Bs0, rb0); }
        }
        if (k + 2 < NIT) {
            if (p == 0) { LOAD_A(k + 2, ra0); LOAD_B(k + 2, rb0); }
            else        { LOAD_A(k + 2, ra1); LOAD_B(k + 2, rb1); }
        }
        if (p == 0) COMPUTE(As0, Bs0);
        else        COMPUTE(As1, Bs1);
        __syncthreads();
    }
#undef LOAD_A
#undef LOAD_B
#undef STORE_A
#undef STORE_B
#undef COMPUTE

    // ---- scatter accumulator into Red (aliases dead As/Bs buffers) ----
    #pragma unroll
    for (int r = 0; r < 16; ++r) {
        const int orow = (r & 3) + 8 * (r >> 2) + 4 * (lane >> 5);
        Red[wv][orow][frow] = acc[r];
    }
    __syncthreads();

    // ---- epilogue: sum 4 wave-partials + bias + time_embed, f4 store ----
    {
        const int rr = tid >> 3;            // 0..31
        const int c0 = (tid & 7) * 4;       // 0..28
        float4 s0 = *(const float4*)&Red[0][rr][c0];
        float4 s1 = *(const float4*)&Red[1][rr][c0];
        float4 s2 = *(const float4*)&Red[2][rr][c0];
        float4 s3 = *(const float4*)&Red[3][rr][c0];
        float4 s;
        s.x = (s0.x + s1.x) + (s2.x + s3.x);
        s.y = (s0.y + s1.y) + (s2.y + s3.y);
        s.z = (s0.z + s1.z) + (s2.z + s3.z);
        s.w = (s0.w + s1.w) + (s2.w + s3.w);
        const int og = row0 + rr;
        const int cb = col0 + c0;
        const int t  = s_times[rr];
        const int tcl = t < (TVOCAB - 1) ? t : (TVOCAB - 1);
        const float4 bi = *(const float4*)(bias + cb);
        const float4 te = *(const float4*)(temb + (size_t)tcl * D_ + cb);
        s.x += bi.x + te.x; s.y += bi.y + te.y;
        s.z += bi.z + te.z; s.w += bi.w + te.w;
        *(float4*)(out_tape + (size_t)og * D_ + cb) = s;
    }
}

// ---------------------------------------------------------------------------
extern "C" void kernel_launch(void* const* d_in, const int* in_sizes, int n_in,
                              void* d_out, int out_size, void* d_ws, size_t ws_size,
                              hipStream_t stream)
{
    const float* h_seq = (const float*)d_in[0];
    const float* z     = (const float*)d_in[1];
    const float* ent   = (const float*)d_in[2];
    const float* W     = (const float*)d_in[3];
    const float* bias  = (const float*)d_in[4];
    const float* temb  = (const float*)d_in[5];

    float* out       = (float*)d_out;
    float* out_tape  = out;                                // 262144
    float* out_valid = out + (size_t)B_ * E_ * D_;         // 256
    float* out_times = out_valid + B_ * E_;                // 256

    k_all<<<256, 256, 0, stream>>>(h_seq, z, ent, W, bias, temb,
                                   out_tape, out_valid, out_times);
}